// Round 15
// baseline (284.894 us; speedup 1.0000x reference)
//
#include <hip/hip_runtime.h>

// Problem: N=32, C=512, H=W=32 (HW=1024), D=256.
// out = x + b_fuse + (Z P^T)/rowsum ; Z = W_fuse * V, P = exp(Q K^T/16).
//
// r15: attn8 + global_load_lds DMA staging of Z (the one untried mechanism).
//  - Q dropped from LDS -> direct L2 gathers (64KB/block panel, L2-hot);
//    frees 67.6KB.
//  - Z staged per 32-key slice into a double-buffered LDS ring via
//    __builtin_amdgcn_global_load_lds (16B/lane, linear dest). Each wave
//    stages its OWN o-rows (ob..ob+64) -> no cross-wave hazard, no barrier;
//    per-wave s_waitcnt vmcnt(4) (counted, never 0 mid-loop) with 1-slice
//    prefetch across the whole kernel (incl. across iterations).
//  - ZP zf reads become LDS b128 reads; in-flight Z bytes no longer cost
//    VGPRs -> deep MLP at the same register budget.
//  - S/softmax numerics identical to r8/r13 (bf16 MFMA, fp32 accum).
//
// Workspace (65 MB): [0,32MB) tp ; [32,64MB) Z ; [64MB,+512K) Wcat ; [+512K,+1MB) Wfuse

#define NB  32
#define CC  512
#define HWD 1024

typedef __attribute__((ext_vector_type(8))) short short8;
typedef __attribute__((ext_vector_type(4))) float f32x4;

__device__ __forceinline__ unsigned short f2bu(float f) {
    unsigned int u = __float_as_uint(f);
    u = (u + 0x7FFFu + ((u >> 16) & 1u)) >> 16;   // RNE to bf16
    return (unsigned short)u;
}

// ---------------- weights pack ----------------
__global__ __launch_bounds__(256) void k_packw(const float* __restrict__ Wt,
                                               const float* __restrict__ Wp,
                                               const float* __restrict__ Wf,
                                               unsigned short* __restrict__ Wcat,
                                               unsigned short* __restrict__ Wfuse) {
    int idx = blockIdx.x * 256 + threadIdx.x;       // 0 .. 262143
    int o = idx >> 9;
    float cv = (o < 256) ? Wt[idx] : Wp[idx - 131072];
    Wcat[idx]  = f2bu(cv);
    Wfuse[idx] = f2bu(Wf[idx]);
}

// ---------------- merged GEMM: embed (y<2) / Z (y>=2) [r8 proven] ----------------
__global__ __launch_bounds__(512) void k_mm(const float* __restrict__ x,
                                            const unsigned short* __restrict__ Wcat,
                                            const unsigned short* __restrict__ Wfuse,
                                            const float* __restrict__ bt,
                                            const float* __restrict__ bp,
                                            unsigned short* __restrict__ tp,
                                            unsigned short* __restrict__ Z) {
    __shared__ __align__(16) float Tr[32 * 132];
    __shared__ __align__(16) unsigned short As[128 * 40];
    __shared__ __align__(16) unsigned short Bs[256 * 40];
    const int m0 = blockIdx.x << 7;
    const int yb = blockIdx.y;
    const bool isZ = (yb >= 2);
    const int n0 = (yb & 1) << 8;
    const unsigned short* W = isZ ? Wfuse : Wcat;
    const int n  = m0 >> 10, qbase = m0 & 1023;
    const int t = threadIdx.x, lane = t & 63, wave = t >> 6;
    const int wr = wave >> 2, wc = wave & 3;
    const int lrow = lane & 15, hi = lane >> 4, lhk = hi << 3;
    const f32x4 fz = {0.f, 0.f, 0.f, 0.f};
    f32x4 acc[4][4];
#pragma unroll
    for (int i = 0; i < 4; ++i)
#pragma unroll
        for (int j = 0; j < 4; ++j) acc[i][j] = fz;

    const int tr_r = t >> 4, tr_q = (t & 15) << 3;
    const int p2_pix = t & 127, p2_c = (t >> 7) << 3;

    for (int kt = 0; kt < 16; ++kt) {
        const int k0 = kt << 5;
        {
            const float* src = x + ((size_t)(n * CC + k0 + tr_r)) * HWD + qbase + tr_q;
            float4 v0 = *(const float4*)(src);
            float4 v1 = *(const float4*)(src + 4);
            *(float4*)(Tr + tr_r * 132 + tr_q) = v0;
            *(float4*)(Tr + tr_r * 132 + tr_q + 4) = v1;
#pragma unroll
            for (int i = 0; i < 2; ++i) {
                int chunk = t + (i << 9);
                int r = chunk >> 2, ko = (chunk & 3) << 3;
                *(uint4*)(Bs + r * 40 + ko) =
                    *(const uint4*)(W + ((size_t)(n0 + r)) * CC + k0 + ko);
            }
        }
        __syncthreads();
        {
            short8 o8;
#pragma unroll
            for (int j = 0; j < 8; ++j)
                o8[j] = (short)f2bu(Tr[(p2_c + j) * 132 + p2_pix]);
            *(short8*)(As + p2_pix * 40 + p2_c) = o8;
        }
        __syncthreads();
        short8 af[4], bfm[4];
#pragma unroll
        for (int mi = 0; mi < 4; ++mi)
            af[mi] = *(const short8*)(As + (wr * 64 + mi * 16 + lrow) * 40 + lhk);
#pragma unroll
        for (int ni = 0; ni < 4; ++ni)
            bfm[ni] = *(const short8*)(Bs + (wc * 64 + ni * 16 + lrow) * 40 + lhk);
#pragma unroll
        for (int mi = 0; mi < 4; ++mi)
#pragma unroll
            for (int ni = 0; ni < 4; ++ni)
                acc[mi][ni] = __builtin_amdgcn_mfma_f32_16x16x32_bf16(
                    af[mi], bfm[ni], acc[mi][ni], 0, 0, 0);
        __syncthreads();
    }
    if (!isZ) {
#pragma unroll
        for (int ni = 0; ni < 4; ++ni) {
            const int col = n0 + wc * 64 + ni * 16 + lrow;
            const float bias = (col < 256) ? bt[col] : bp[col - 256];
#pragma unroll
            for (int mi = 0; mi < 4; ++mi)
#pragma unroll
                for (int j = 0; j < 4; ++j) {
                    const int row = m0 + wr * 64 + mi * 16 + hi * 4 + j;
                    tp[(size_t)row * CC + col] = f2bu(acc[mi][ni][j] + bias);
                }
        }
    } else {
        const int kbase = qbase + wr * 64;
        unsigned short* Zn = Z + (size_t)n * CC * HWD;
#pragma unroll
        for (int ni = 0; ni < 4; ++ni) {
            const int o = n0 + wc * 64 + ni * 16 + lrow;
#pragma unroll
            for (int mi = 0; mi < 4; ++mi) {
                ushort4 v;
                v.x = f2bu(acc[mi][ni][0]);
                v.y = f2bu(acc[mi][ni][1]);
                v.z = f2bu(acc[mi][ni][2]);
                v.w = f2bu(acc[mi][ni][3]);
                *(ushort4*)(Zn + (size_t)o * HWD + kbase + mi * 16 + (hi << 2)) = v;
            }
        }
    }
}

// ---------------- attention: out = x + b + (Z P^T)/rowsum ----------------
// 8 waves, 128-query tile, 4 iters of 256 keys, 256 blocks = 1/CU.
// Q direct from L2; Z DMA-staged per 32-key slice (per-wave, dbuf, vmcnt(4)).
__global__ __launch_bounds__(512, 2) void k_attn12(const unsigned short* __restrict__ tp,
                                                   const unsigned short* __restrict__ Z,
                                                   const float* __restrict__ bfu,
                                                   const float* __restrict__ x,
                                                   float* __restrict__ out) {
    constexpr int PST = 264;                       // P row stride (bf16)
    constexpr int PSZB = 128 * PST * 2;            // 67,584 B
    constexpr int ZBUF = 512 * 32;                 // ushorts per slice buffer
    __shared__ __align__(16) unsigned char SLB[PSZB + 2 * ZBUF * 2];  // 133,120 B
    __shared__ float rowsum[128];
    unsigned short* P  = (unsigned short*)SLB;     // [128][264]
    unsigned short* ZB = (unsigned short*)(SLB + PSZB);  // 2 x [512][32]

    const int b = blockIdx.x;
    const int n = b & 31;                          // XCD = n % 8
    const int q0 = (b >> 5) << 7;
    const int t = threadIdx.x, lane = t & 63, wave = t >> 6;
    const int lrow = lane & 15, hi = lane >> 4, lhk = hi << 3;
    const f32x4 fz = {0.f, 0.f, 0.f, 0.f};

    const unsigned short* tpn = tp + (size_t)n * HWD * CC;
    const unsigned short* Zn  = Z + (size_t)n * CC * HWD;

    // per-wave Z slice staging: slice g covers keys [g*32, g*32+32) of this
    // wave's own o-rows [wave*64, wave*64+64). Linear LDS dest (lane x 16B).
    const int srl = lane >> 2, scl = lane & 3;     // staging row-in-16 / chunk
    auto stage_slice = [&](int g) {
        const int rbase = wave << 6;
        unsigned short* lbase = ZB + (size_t)(g & 1) * ZBUF;
#pragma unroll
        for (int i = 0; i < 4; ++i) {
            const unsigned short* gsrc =
                Zn + (size_t)(rbase + (i << 4) + srl) * HWD + g * 32 + scl * 8;
            unsigned short* ldst = lbase + (size_t)(rbase + (i << 4)) * 32;
            __builtin_amdgcn_global_load_lds(
                (__attribute__((address_space(1))) void*)(void*)const_cast<unsigned short*>(gsrc),
                (__attribute__((address_space(3))) void*)ldst, 16, 0, 0);
        }
    };

    if (t < 128) rowsum[t] = 0.f;
    stage_slice(0);                                // prefetch iter-0 slice 0
    __syncthreads();                               // rowsum zero visible

    f32x4 accG[8][4];                              // [qj][mi]: row=q, col=o
#pragma unroll
    for (int qj = 0; qj < 8; ++qj)
#pragma unroll
        for (int mi = 0; mi < 4; ++mi) accG[qj][mi] = fz;

    const int kw = wave << 4;                      // wave's 16-key slot per 128-sub
    const int ob = wave << 6;                      // wave's 64-output (o) range

    for (int it = 0; it < 4; ++it) {
        const int kv0 = it << 8;
        const size_t krow0 = (size_t)(kv0 + kw + lrow) * CC + 256;
        const size_t krow1 = (size_t)(kv0 + 128 + kw + lrow) * CC + 256;
        // ---- S phase: Q direct from L2, kfr pair per kt ----
        f32x4 accA[2][8];
#pragma unroll
        for (int k2 = 0; k2 < 2; ++k2)
#pragma unroll
            for (int qj = 0; qj < 8; ++qj) accA[k2][qj] = fz;
#pragma unroll
        for (int kt = 0; kt < 8; ++kt) {
            const int d0 = (kt << 5) + lhk;
            short8 kf0 = *(const short8*)(tpn + krow0 + d0);
            short8 kf1 = *(const short8*)(tpn + krow1 + d0);
#pragma unroll
            for (int qj = 0; qj < 8; ++qj) {
                short8 qfr = *(const short8*)(tpn + (size_t)(q0 + qj * 16 + lrow) * CC + d0);
                accA[0][qj] = __builtin_amdgcn_mfma_f32_16x16x32_bf16(qfr, kf0, accA[0][qj], 0, 0, 0);
                accA[1][qj] = __builtin_amdgcn_mfma_f32_16x16x32_bf16(qfr, kf1, accA[1][qj], 0, 0, 0);
            }
        }
        // exp -> P, psum -> rowsum (transient, immediate fold: r8 budget)
        float psum[8][4];
#pragma unroll
        for (int qj = 0; qj < 8; ++qj)
#pragma unroll
            for (int j = 0; j < 4; ++j) psum[qj][j] = 0.f;
#pragma unroll
        for (int k2 = 0; k2 < 2; ++k2) {
            const int pcol = (k2 << 7) + kw + lrow;
#pragma unroll
            for (int qj = 0; qj < 8; ++qj)
#pragma unroll
                for (int j = 0; j < 4; ++j) {
                    float p = __expf(accA[k2][qj][j] * 0.0625f);
                    psum[qj][j] += p;
                    P[(qj * 16 + hi * 4 + j) * PST + pcol] = f2bu(p);
                }
        }
#pragma unroll
        for (int qj = 0; qj < 8; ++qj)
#pragma unroll
            for (int j = 0; j < 4; ++j) {
                float s = psum[qj][j];
                s += __shfl_xor(s, 1, 16);
                s += __shfl_xor(s, 2, 16);
                s += __shfl_xor(s, 4, 16);
                s += __shfl_xor(s, 8, 16);
                if (lrow == 0) atomicAdd(&rowsum[qj * 16 + hi * 4 + j], s);
            }
        __syncthreads();                           // P complete (drains vmcnt too)
        // ---- ZP phase: accG[q][o] += P . Z^T, Z from DMA-staged LDS ----
        __builtin_amdgcn_s_setprio(1);
#pragma unroll
        for (int ks = 0; ks < 8; ++ks) {
            const int g = (it << 3) + ks;
            if (g + 1 < 32) stage_slice(g + 1);    // prefetch next slice (4 DMA)
            if (g + 1 < 32) {
                asm volatile("s_waitcnt vmcnt(4)" ::: "memory");  // slice g ready
            } else {
                asm volatile("s_waitcnt vmcnt(0)" ::: "memory");  // last slice
            }
            __builtin_amdgcn_sched_barrier(0);
            const unsigned short* zb = ZB + (size_t)(g & 1) * ZBUF;
            short8 zf[4];
#pragma unroll
            for (int mi = 0; mi < 4; ++mi)
                zf[mi] = *(const short8*)(zb + (size_t)(ob + mi * 16 + lrow) * 32 + lhk);
            const int kb = (ks << 5) + lhk;
#pragma unroll
            for (int qj = 0; qj < 8; ++qj) {
                short8 pa = *(const short8*)(P + (qj * 16 + lrow) * PST + kb);
#pragma unroll
                for (int mi = 0; mi < 4; ++mi)
                    accG[qj][mi] = __builtin_amdgcn_mfma_f32_16x16x32_bf16(
                        pa, zf[mi], accG[qj][mi], 0, 0, 0);
            }
        }
        __builtin_amdgcn_s_setprio(0);
        __syncthreads();                           // P consumed; atomics drained
    }

    // ---- epilogue: out[n, o, q] = x + b_fuse[o] + accG / rowsum[q] ----
    if (t < 128) rowsum[t] = 1.f / rowsum[t];
    __syncthreads();
    float bias[4];
#pragma unroll
    for (int mi = 0; mi < 4; ++mi) bias[mi] = bfu[ob + mi * 16 + lrow];
#pragma unroll
    for (int qj = 0; qj < 8; ++qj) {
        const float4 inv4 = *(const float4*)&rowsum[qj * 16 + (hi << 2)];
#pragma unroll
        for (int mi = 0; mi < 4; ++mi) {
            const int o = ob + mi * 16 + lrow;
            const size_t idx = ((size_t)(n * CC + o)) * HWD + q0 + qj * 16 + (hi << 2);
            const float4 xr = *(const float4*)(x + idx);
            float4 r;
            r.x = accG[qj][mi][0] * inv4.x + bias[mi] + xr.x;
            r.y = accG[qj][mi][1] * inv4.y + bias[mi] + xr.y;
            r.z = accG[qj][mi][2] * inv4.z + bias[mi] + xr.z;
            r.w = accG[qj][mi][3] * inv4.w + bias[mi] + xr.w;
            *(float4*)(out + idx) = r;
        }
    }
}

extern "C" void kernel_launch(void* const* d_in, const int* in_sizes, int n_in,
                              void* d_out, int out_size, void* d_ws, size_t ws_size,
                              hipStream_t stream) {
    const float* x  = (const float*)d_in[0];
    const float* Wt = (const float*)d_in[1];
    const float* bt = (const float*)d_in[2];
    const float* Wp = (const float*)d_in[3];
    const float* bp = (const float*)d_in[4];
    const float* Wf = (const float*)d_in[5];
    const float* bfu = (const float*)d_in[6];
    float* out = (float*)d_out;

    char* ws = (char*)d_ws;
    unsigned short* tp    = (unsigned short*)(ws);                 // 32 MB
    unsigned short* Z     = (unsigned short*)(ws + 33554432);      // 32 MB
    unsigned short* Wcat  = (unsigned short*)(ws + 67108864);      // 512 KB
    unsigned short* Wfuse = (unsigned short*)(ws + 67633152);      // 512 KB

    k_packw <<<dim3(1024), 256, 0, stream>>>(Wt, Wp, Wf, Wcat, Wfuse);
    k_mm    <<<dim3(256, 4), 512, 0, stream>>>(x, Wcat, Wfuse, bt, bp, tp, Z);
    k_attn12<<<dim3(256), 512, 0, stream>>>(tp, Z, bfu, x, out);
}

// Round 16
// 170.241 us; speedup vs baseline: 1.6735x; 1.6735x over previous
//
#include <hip/hip_runtime.h>

// Problem: N=32, C=512, H=W=32 (HW=1024), D=256.
// out = x + b_fuse + (Z P^T)/rowsum ; Z = W_fuse * V, P = exp(Q K^T/16).
//
// FINAL locked configuration (r8, reproduced r13 at 170.4us):
//  k_packw : weights -> bf16
//  k_mm    : merged embed GEMM (tp = [theta|phi]) + Z GEMM, grid (256,4)
//  k_attn8 : per (n, 128-query tile), 8 waves, 256 blocks (exactly 1/CU).
//            4 iters of 256 keys: S phase (both 128-key subtiles per pass,
//            kfr pair loaded once per kt, qfr reused x2, accA[2][8]) -> P LDS
//            [128][264]; ZP phase swapped-operand mfma(pa, zf) -> accG[8][4]
//            (q-major output -> float4 stores + residual loads).
//
// Falsified-alternatives ledger (15 rounds):
//   q-tile 32/64 (r5/r6/r7), occupancy 1-4 wv/SIMD (r4/r5/r7), register
//   prefetch (r7), LBAR lgkmcnt-only barriers (r12), persistent psum (r9,
//   spills), dual-acc k_mm fusion (r10), split S/ZP pure GEMMs (r11),
//   fp8 ZP (r14, slow + absmax 0.10), global_load_lds DMA + Q-from-L2 (r15).
//   Structure is resource-cornered: LDS (Q+P, K/Z each read once) and VGPR
//   (accG+accA at 256 ceiling) both exhausted; remaining stall is L2/L3
//   gather latency at 2 waves/SIMD.
//
// Workspace (65 MB): [0,32MB) tp ; [32,64MB) Z ; [64MB,+512K) Wcat ; [+512K,+1MB) Wfuse

#define NB  32
#define CC  512
#define HWD 1024

typedef __attribute__((ext_vector_type(8))) short short8;
typedef __attribute__((ext_vector_type(4))) float f32x4;

__device__ __forceinline__ unsigned short f2bu(float f) {
    unsigned int u = __float_as_uint(f);
    u = (u + 0x7FFFu + ((u >> 16) & 1u)) >> 16;   // RNE to bf16
    return (unsigned short)u;
}

// ---------------- weights pack ----------------
__global__ __launch_bounds__(256) void k_packw(const float* __restrict__ Wt,
                                               const float* __restrict__ Wp,
                                               const float* __restrict__ Wf,
                                               unsigned short* __restrict__ Wcat,
                                               unsigned short* __restrict__ Wfuse) {
    int idx = blockIdx.x * 256 + threadIdx.x;       // 0 .. 262143
    int o = idx >> 9;
    float cv = (o < 256) ? Wt[idx] : Wp[idx - 131072];
    Wcat[idx]  = f2bu(cv);
    Wfuse[idx] = f2bu(Wf[idx]);
}

// ---------------- merged GEMM: embed (y<2) / Z (y>=2) ----------------
// M-tile 128 pixels (transpose-staged from fp32 x), N-tile 256.
__global__ __launch_bounds__(512) void k_mm(const float* __restrict__ x,
                                            const unsigned short* __restrict__ Wcat,
                                            const unsigned short* __restrict__ Wfuse,
                                            const float* __restrict__ bt,
                                            const float* __restrict__ bp,
                                            unsigned short* __restrict__ tp,
                                            unsigned short* __restrict__ Z) {
    __shared__ __align__(16) float Tr[32 * 132];                 // 16896 B
    __shared__ __align__(16) unsigned short As[128 * 40];        // 10240 B
    __shared__ __align__(16) unsigned short Bs[256 * 40];        // 20480 B
    const int m0 = blockIdx.x << 7;                // global pixel row base
    const int yb = blockIdx.y;
    const bool isZ = (yb >= 2);
    const int n0 = (yb & 1) << 8;                  // col base (0 or 256)
    const unsigned short* W = isZ ? Wfuse : Wcat;
    const int n  = m0 >> 10, qbase = m0 & 1023;
    const int t = threadIdx.x, lane = t & 63, wave = t >> 6;
    const int wr = wave >> 2, wc = wave & 3;
    const int lrow = lane & 15, hi = lane >> 4, lhk = hi << 3;
    const f32x4 fz = {0.f, 0.f, 0.f, 0.f};
    f32x4 acc[4][4];
#pragma unroll
    for (int i = 0; i < 4; ++i)
#pragma unroll
        for (int j = 0; j < 4; ++j) acc[i][j] = fz;

    const int tr_r = t >> 4, tr_q = (t & 15) << 3;        // Tr stage
    const int p2_pix = t & 127, p2_c = (t >> 7) << 3;     // transpose

    for (int kt = 0; kt < 16; ++kt) {
        const int k0 = kt << 5;
        {
            const float* src = x + ((size_t)(n * CC + k0 + tr_r)) * HWD + qbase + tr_q;
            float4 v0 = *(const float4*)(src);
            float4 v1 = *(const float4*)(src + 4);
            *(float4*)(Tr + tr_r * 132 + tr_q) = v0;
            *(float4*)(Tr + tr_r * 132 + tr_q + 4) = v1;
#pragma unroll
            for (int i = 0; i < 2; ++i) {
                int chunk = t + (i << 9);
                int r = chunk >> 2, ko = (chunk & 3) << 3;
                *(uint4*)(Bs + r * 40 + ko) =
                    *(const uint4*)(W + ((size_t)(n0 + r)) * CC + k0 + ko);
            }
        }
        __syncthreads();
        {
            short8 o8;
#pragma unroll
            for (int j = 0; j < 8; ++j)
                o8[j] = (short)f2bu(Tr[(p2_c + j) * 132 + p2_pix]);
            *(short8*)(As + p2_pix * 40 + p2_c) = o8;
        }
        __syncthreads();
        short8 af[4], bfm[4];
#pragma unroll
        for (int mi = 0; mi < 4; ++mi)
            af[mi] = *(const short8*)(As + (wr * 64 + mi * 16 + lrow) * 40 + lhk);
#pragma unroll
        for (int ni = 0; ni < 4; ++ni)
            bfm[ni] = *(const short8*)(Bs + (wc * 64 + ni * 16 + lrow) * 40 + lhk);
#pragma unroll
        for (int mi = 0; mi < 4; ++mi)
#pragma unroll
            for (int ni = 0; ni < 4; ++ni)
                acc[mi][ni] = __builtin_amdgcn_mfma_f32_16x16x32_bf16(
                    af[mi], bfm[ni], acc[mi][ni], 0, 0, 0);
        __syncthreads();
    }
    if (!isZ) {
#pragma unroll
        for (int ni = 0; ni < 4; ++ni) {
            const int col = n0 + wc * 64 + ni * 16 + lrow;
            const float bias = (col < 256) ? bt[col] : bp[col - 256];
#pragma unroll
            for (int mi = 0; mi < 4; ++mi)
#pragma unroll
                for (int j = 0; j < 4; ++j) {
                    const int row = m0 + wr * 64 + mi * 16 + hi * 4 + j;
                    tp[(size_t)row * CC + col] = f2bu(acc[mi][ni][j] + bias);
                }
        }
    } else {
        const int kbase = qbase + wr * 64;
        unsigned short* Zn = Z + (size_t)n * CC * HWD;
#pragma unroll
        for (int ni = 0; ni < 4; ++ni) {
            const int o = n0 + wc * 64 + ni * 16 + lrow;
#pragma unroll
            for (int mi = 0; mi < 4; ++mi) {
                ushort4 v;
                v.x = f2bu(acc[mi][ni][0]);
                v.y = f2bu(acc[mi][ni][1]);
                v.z = f2bu(acc[mi][ni][2]);
                v.w = f2bu(acc[mi][ni][3]);
                *(ushort4*)(Zn + (size_t)o * HWD + kbase + mi * 16 + (hi << 2)) = v;
            }
        }
    }
}

// ---------------- attention: out = x + b + (Z P^T)/rowsum ----------------
// 8 waves, 128-query tile, 4 iters of 256 keys, 256 blocks = 1/CU.
__global__ __launch_bounds__(512, 2) void k_attn8(const unsigned short* __restrict__ tp,
                                                  const unsigned short* __restrict__ Z,
                                                  const float* __restrict__ bfu,
                                                  const float* __restrict__ x,
                                                  float* __restrict__ out) {
    constexpr int QST = 264;
    constexpr int PST = 264;
    constexpr int QSZ = 128 * QST;
    __shared__ __align__(16) unsigned short SL[QSZ + 128 * PST];  // 135,168 B
    __shared__ float rowsum[128];
    unsigned short* Qs = SL;                       // [128][264]
    unsigned short* P  = SL + QSZ;                 // [128][264] (256 keys + pad)

    const int b = blockIdx.x;
    const int n = b & 31;                          // XCD = b%8 = n%8 -> 4 batches/XCD
    const int q0 = (b >> 5) << 7;                  // 8 q-tiles of 128
    const int t = threadIdx.x, lane = t & 63, wave = t >> 6;
    const int lrow = lane & 15, hi = lane >> 4, lhk = hi << 3;
    const f32x4 fz = {0.f, 0.f, 0.f, 0.f};

    const unsigned short* tpn = tp + (size_t)n * HWD * CC;
    const unsigned short* Zn  = Z + (size_t)n * CC * HWD;

    if (t < 128) rowsum[t] = 0.f;
    // stage Q tile: rows q0..q0+127, d 0..255 (coalesced row-major)
#pragma unroll
    for (int pass = 0; pass < 8; ++pass) {
        int chunk = (pass << 9) + t;               // 0..4095
        int row = chunk >> 5, co = (chunk & 31) << 3;
        *(short8*)(Qs + row * QST + co) =
            *(const short8*)(tpn + (size_t)(q0 + row) * CC + co);
    }
    __syncthreads();

    f32x4 accG[8][4];                              // [qj][mi]: row=q, col=o
#pragma unroll
    for (int qj = 0; qj < 8; ++qj)
#pragma unroll
        for (int mi = 0; mi < 4; ++mi) accG[qj][mi] = fz;

    const int kw = wave << 4;                      // wave's 16-key slot per 128-sub
    const int ob = wave << 6;                      // wave's 64-output (o) range

    for (int it = 0; it < 4; ++it) {
        const int kv0 = it << 8;                   // 256-key iter base
        const size_t krow0 = (size_t)(kv0 + kw + lrow) * CC + 256;
        const size_t krow1 = (size_t)(kv0 + 128 + kw + lrow) * CC + 256;
        // ---- S phase: both 128-key subtiles, kfr pair loaded once per kt ----
        f32x4 accA[2][8];
#pragma unroll
        for (int k2 = 0; k2 < 2; ++k2)
#pragma unroll
            for (int qj = 0; qj < 8; ++qj) accA[k2][qj] = fz;
#pragma unroll
        for (int kt = 0; kt < 8; ++kt) {
            const int d0 = (kt << 5) + lhk;
            short8 kf0 = *(const short8*)(tpn + krow0 + d0);
            short8 kf1 = *(const short8*)(tpn + krow1 + d0);
#pragma unroll
            for (int qj = 0; qj < 8; ++qj) {
                short8 qfr = *(const short8*)(Qs + (qj * 16 + lrow) * QST + d0);
                accA[0][qj] = __builtin_amdgcn_mfma_f32_16x16x32_bf16(qfr, kf0, accA[0][qj], 0, 0, 0);
                accA[1][qj] = __builtin_amdgcn_mfma_f32_16x16x32_bf16(qfr, kf1, accA[1][qj], 0, 0, 0);
            }
        }
        // exp -> P, psum -> rowsum
        float psum[8][4];
#pragma unroll
        for (int qj = 0; qj < 8; ++qj)
#pragma unroll
            for (int j = 0; j < 4; ++j) psum[qj][j] = 0.f;
#pragma unroll
        for (int k2 = 0; k2 < 2; ++k2) {
            const int pcol = (k2 << 7) + kw + lrow;
#pragma unroll
            for (int qj = 0; qj < 8; ++qj)
#pragma unroll
                for (int j = 0; j < 4; ++j) {
                    float p = __expf(accA[k2][qj][j] * 0.0625f);
                    psum[qj][j] += p;
                    P[(qj * 16 + hi * 4 + j) * PST + pcol] = f2bu(p);
                }
        }
#pragma unroll
        for (int qj = 0; qj < 8; ++qj)
#pragma unroll
            for (int j = 0; j < 4; ++j) {
                float s = psum[qj][j];
                s += __shfl_xor(s, 1, 16);
                s += __shfl_xor(s, 2, 16);
                s += __shfl_xor(s, 4, 16);
                s += __shfl_xor(s, 8, 16);
                if (lrow == 0) atomicAdd(&rowsum[qj * 16 + hi * 4 + j], s);
            }
        __syncthreads();                           // P complete
        // ---- ZP phase: accG[q][o] += P . Z^T (swapped operands) ----
        __builtin_amdgcn_s_setprio(1);
#pragma unroll
        for (int ks = 0; ks < 8; ++ks) {
            const int kb = (ks << 5) + lhk;
            short8 zf[4];
#pragma unroll
            for (int mi = 0; mi < 4; ++mi)
                zf[mi] = *(const short8*)(Zn + (size_t)(ob + mi * 16 + lrow) * HWD + kv0 + kb);
#pragma unroll
            for (int qj = 0; qj < 8; ++qj) {
                short8 pa = *(const short8*)(P + (qj * 16 + lrow) * PST + kb);
#pragma unroll
                for (int mi = 0; mi < 4; ++mi)
                    accG[qj][mi] = __builtin_amdgcn_mfma_f32_16x16x32_bf16(
                        pa, zf[mi], accG[qj][mi], 0, 0, 0);
            }
        }
        __builtin_amdgcn_s_setprio(0);
        __syncthreads();                           // P consumed; atomics drained
    }

    // ---- epilogue: out[n, o, q] = x + b_fuse[o] + accG / rowsum[q] ----
    if (t < 128) rowsum[t] = 1.f / rowsum[t];
    __syncthreads();
    float bias[4];
#pragma unroll
    for (int mi = 0; mi < 4; ++mi) bias[mi] = bfu[ob + mi * 16 + lrow];
#pragma unroll
    for (int qj = 0; qj < 8; ++qj) {
        const float4 inv4 = *(const float4*)&rowsum[qj * 16 + (hi << 2)];
#pragma unroll
        for (int mi = 0; mi < 4; ++mi) {
            const int o = ob + mi * 16 + lrow;
            const size_t idx = ((size_t)(n * CC + o)) * HWD + q0 + qj * 16 + (hi << 2);
            const float4 xr = *(const float4*)(x + idx);
            float4 r;
            r.x = accG[qj][mi][0] * inv4.x + bias[mi] + xr.x;
            r.y = accG[qj][mi][1] * inv4.y + bias[mi] + xr.y;
            r.z = accG[qj][mi][2] * inv4.z + bias[mi] + xr.z;
            r.w = accG[qj][mi][3] * inv4.w + bias[mi] + xr.w;
            *(float4*)(out + idx) = r;
        }
    }
}

extern "C" void kernel_launch(void* const* d_in, const int* in_sizes, int n_in,
                              void* d_out, int out_size, void* d_ws, size_t ws_size,
                              hipStream_t stream) {
    const float* x  = (const float*)d_in[0];
    const float* Wt = (const float*)d_in[1];
    const float* bt = (const float*)d_in[2];
    const float* Wp = (const float*)d_in[3];
    const float* bp = (const float*)d_in[4];
    const float* Wf = (const float*)d_in[5];
    const float* bfu = (const float*)d_in[6];
    float* out = (float*)d_out;

    char* ws = (char*)d_ws;
    unsigned short* tp    = (unsigned short*)(ws);                 // 32 MB
    unsigned short* Z     = (unsigned short*)(ws + 33554432);      // 32 MB
    unsigned short* Wcat  = (unsigned short*)(ws + 67108864);      // 512 KB
    unsigned short* Wfuse = (unsigned short*)(ws + 67633152);      // 512 KB

    k_packw<<<dim3(1024), 256, 0, stream>>>(Wt, Wp, Wf, Wcat, Wfuse);
    k_mm   <<<dim3(256, 4), 512, 0, stream>>>(x, Wcat, Wfuse, bt, bp, tp, Z);
    k_attn8<<<dim3(256), 512, 0, stream>>>(tp, Z, bfu, x, out);
}